// Round 17
// baseline (96.633 us; speedup 1.0000x reference)
//
#include <hip/hip_runtime.h>
#include <hip/hip_bf16.h>

#define BB 4
#define NN 4096
#define DD 256
#define MM (BB * NN)      // 16384 rows
#define MAXNZ 128
// grid: 1024 groups x 7 blocks = 3 GEMM + 4 deg (deg block = 4 waves = 4 rows)
#define GPER 7
#define TOTAL_BLKS (1024 * GPER)   // 7168

using bf16x8 = __attribute__((ext_vector_type(8))) __bf16;
using f32x4  = __attribute__((ext_vector_type(4))) float;
using f32x4e = __attribute__((ext_vector_type(4))) float;
using u16x8e = __attribute__((ext_vector_type(8))) unsigned short;

__device__ __forceinline__ unsigned short f2bf(float f) {
    union { float f; unsigned u; } x; x.f = f;
    unsigned r = x.u + 0x7fffu + ((x.u >> 16) & 1u);
    return (unsigned short)(r >> 16);
}
__device__ __forceinline__ float bf2f(unsigned short s) {
    union { unsigned u; float f; } x; x.u = ((unsigned)s) << 16;
    return x.f;
}

__device__ __forceinline__ void gload16(const void* g, void* l) {
    __builtin_amdgcn_global_load_lds(
        (const __attribute__((address_space(1))) unsigned int*)g,
        (__attribute__((address_space(3))) unsigned int*)l,
        16, 0, 0);
}

// ---------------- kernel 0: weights-only bf16 transpose-convert ----------------
// R17: x-conversion eliminated (GEMM stages A from fp32 directly); cvt shrinks
// 4288 -> 192 blocks.
__global__ __launch_bounds__(256) void k_cvt(const float* __restrict__ theta,
                                             const float* __restrict__ Wh,
                                             const float* __restrict__ Wt,
                                             unsigned short* __restrict__ wb) {
    int wt = blockIdx.x * 256 + threadIdx.x;     // 0..49151
    int s   = wt >> 14;                          // 0..2
    int rem = wt & 16383;
    int k   = rem >> 6;                          // 0..255
    int n4  = (rem & 63) << 2;                   // 0..252
    const float* W = (s == 0) ? theta : ((s == 1) ? Wh : Wt);
    f32x4e v = __builtin_nontemporal_load((const f32x4e*)(W + k * DD + n4));
    unsigned short* dst = wb + ((size_t)s << 16);
    dst[(size_t)(n4 + 0) * DD + k] = f2bf(v[0]);
    dst[(size_t)(n4 + 1) * DD + k] = f2bf(v[1]);
    dst[(size_t)(n4 + 2) * DD + k] = f2bf(v[2]);
    dst[(size_t)(n4 + 3) * DD + k] = f2bf(v[3]);
}

// ------------- fused kernel: deg scan + triple GEMM -------------
// R17: GEMM A-tile staged from fp32 x with in-register f2bf + swizzled ds_write
// reproducing the exact gload_lds layout contract:
//   LDS byte of (row r, col-byte cb) = r*128 + (cb ^ ((r&7)<<4))
// ds_read/MFMA path unchanged. B still gload_lds from wb.
__global__ __launch_bounds__(256) void k_prep(const float* __restrict__ x,
                                              const unsigned short* __restrict__ wb,
                                              const float* __restrict__ bt,
                                              const float* __restrict__ adj,
                                              float* __restrict__ norm,
                                              int* __restrict__ cnt,
                                              unsigned short* __restrict__ idx,
                                              unsigned short* __restrict__ h,
                                              unsigned short* __restrict__ het,
                                              unsigned short* __restrict__ gate) {
    __shared__ __align__(16) unsigned short AB[8192];     // A [0,4096), B [4096,8192) ushorts

    const int bx  = blockIdx.x;
    const int q   = bx / GPER;
    const int r   = bx % GPER;
    const int tid = threadIdx.x;
    const int wave = tid >> 6;
    const int lane = tid & 63;

    if (r < 3) {
        // ---------------- GEMM role ----------------
        const int g   = q * 3 + r;
        const int m0  = (g / 12) * 64;
        const int yb  = g % 12;
        const int seg = yb >> 2;                // 0:theta 1:Wh 2:Wt
        const int n0  = (yb & 3) * 64;

        const int lm = lane & 15;
        const int kg = lane >> 4;
        const int wm = (wave >> 1) * 32;
        const int wn = (wave & 1) * 32;

        const int rsub = lane >> 3;
        const int ksw  = 8 * ((lane & 7) ^ rsub);

        const unsigned short* wseg = wb + ((size_t)seg << 16);

        // A-staging coords: thread -> (row, 16-col quarter)
        const int arow  = tid >> 2;             // 0..63
        const int acolq = (tid & 3) * 16;       // 0,16,32,48
        const int asw   = (arow & 7) << 4;
        char* arb = (char*)AB + arow * 128;

        f32x4 acc[2][2] = {};

        for (int kt = 0; kt < 4; ++kt) {
            const int k0 = kt * 64;
            // stage A: fp32 x -> bf16, swizzled ds_write (16 elems/thread)
            {
                const float* xs = x + (size_t)(m0 + arow) * DD + k0 + acolq;
                float4 f0 = *(const float4*)(xs + 0);
                float4 f1 = *(const float4*)(xs + 4);
                float4 f2 = *(const float4*)(xs + 8);
                float4 f3 = *(const float4*)(xs + 12);
                u16x8e c0, c1;
                c0[0] = f2bf(f0.x); c0[1] = f2bf(f0.y); c0[2] = f2bf(f0.z); c0[3] = f2bf(f0.w);
                c0[4] = f2bf(f1.x); c0[5] = f2bf(f1.y); c0[6] = f2bf(f1.z); c0[7] = f2bf(f1.w);
                c1[0] = f2bf(f2.x); c1[1] = f2bf(f2.y); c1[2] = f2bf(f2.z); c1[3] = f2bf(f2.w);
                c1[4] = f2bf(f3.x); c1[5] = f2bf(f3.y); c1[6] = f2bf(f3.z); c1[7] = f2bf(f3.w);
                *(u16x8e*)(arb + ((acolq * 2) ^ asw))      = c0;
                *(u16x8e*)(arb + ((acolq * 2 + 16) ^ asw)) = c1;
            }
            // stage B via gload_lds from wb (unchanged)
#pragma unroll
            for (int it = 0; it < 2; ++it) {
                int t = wave * 2 + it;
                const unsigned short* gb = wseg + (size_t)(n0 + t * 8 + rsub) * DD + k0 + ksw;
                gload16(gb, &AB[4096 + t * 512]);
            }
            __syncthreads();
#pragma unroll
            for (int ks = 0; ks < 2; ++ks) {
                const int cb = ks * 64 + kg * 16;
                bf16x8 a[2], b[2];
#pragma unroll
                for (int i = 0; i < 2; ++i) {
                    int rw = wm + i * 16 + lm;
                    a[i] = *(const bf16x8*)((const char*)AB + rw * 128 + (cb ^ ((rw & 7) << 4)));
                }
#pragma unroll
                for (int j = 0; j < 2; ++j) {
                    int rw = wn + j * 16 + lm;
                    b[j] = *(const bf16x8*)((const char*)AB + 8192 + rw * 128 + (cb ^ ((rw & 7) << 4)));
                }
#pragma unroll
                for (int i = 0; i < 2; ++i)
#pragma unroll
                    for (int j = 0; j < 2; ++j)
                        acc[i][j] = __builtin_amdgcn_mfma_f32_16x16x32_bf16(a[i], b[j], acc[i][j], 0, 0, 0);
            }
            __syncthreads();
        }

        const int rbase = (lane >> 4) * 4;
#pragma unroll
        for (int i = 0; i < 2; ++i) {
#pragma unroll
            for (int j = 0; j < 2; ++j) {
                int cseg = n0 + wn + j * 16 + lm;
#pragma unroll
                for (int rr = 0; rr < 4; ++rr) {
                    int grow = m0 + wm + i * 16 + rbase + rr;
                    float v = acc[i][j][rr];
                    size_t off = (size_t)grow * DD + cseg;
                    if (seg == 0) {
                        h[off] = f2bf(v);
                    } else if (seg == 1) {
                        het[off] = f2bf(v);
                    } else {
                        float gt = 1.f / (1.f + expf(-(v + bt[cseg])));
                        gate[off] = f2bf(gt);
                    }
                }
            }
        }
    } else {
        // -------- deg role: wave-per-row, register compaction (unchanged) --------
        const int drow = (q * 4 + (r - 3)) * 4 + wave;
        const float4* arow4 = (const float4*)(adj + (size_t)drow * NN);

        unsigned long long mask = 0ull;
#pragma unroll 1
        for (int hf = 0; hf < 2; ++hf) {
            float4 v[8];
#pragma unroll
            for (int s = 0; s < 8; ++s) v[s] = arow4[hf * 512 + s * 64 + lane];
#pragma unroll
            for (int s = 0; s < 8; ++s) {
                int base = 4 * (hf * 8 + s);
                if (v[s].x != 0.f) mask |= 1ull << (base + 0);
                if (v[s].y != 0.f) mask |= 1ull << (base + 1);
                if (v[s].z != 0.f) mask |= 1ull << (base + 2);
                if (v[s].w != 0.f) mask |= 1ull << (base + 3);
            }
        }

        const int cntl = __popcll(mask);
        int inc = cntl;
#pragma unroll
        for (int d = 1; d < 64; d <<= 1) {
            int t = __shfl_up(inc, d);
            if (lane >= d) inc += t;
        }
        const int excl  = inc - cntl;
        const int total = __shfl(inc, 63);

        unsigned long long m = mask;
        int slot = excl;
        while (m) {
            int bpos = __ffsll((unsigned long long)m) - 1;
            m &= m - 1;
            if (slot < MAXNZ) {
                int col = ((bpos >> 2) << 8) + (lane << 2) + (bpos & 3);
                idx[(size_t)drow * MAXNZ + slot] = (unsigned short)col;
            }
            ++slot;
        }
        if (lane == 0) {
            cnt[drow]  = total < MAXNZ ? total : MAXNZ;
            norm[drow] = rsqrtf((float)total + 1e-6f);
        }
    }
}

// ---------------- kernel 2: gather-SpMM + blend + ELU (unchanged) ----------------
__global__ __launch_bounds__(256) void k_spmm(const unsigned short* __restrict__ h,
                                              const unsigned short* __restrict__ het,
                                              const unsigned short* __restrict__ gate,
                                              const float* __restrict__ norm,
                                              const int* __restrict__ cnt,
                                              const unsigned short* __restrict__ idx,
                                              float* __restrict__ out) {
    __shared__ unsigned short sj[4][MAXNZ];
    __shared__ float sn[4][MAXNZ];
    const int wave = threadIdx.x >> 6;
    const int lane = threadIdx.x & 63;
    const int half = lane >> 5;
    const int l32  = lane & 31;
    const int row  = blockIdx.x * 4 + wave;
    const int b    = row >> 12;
    int c = cnt[row];
    if (c > MAXNZ) c = MAXNZ;
    const unsigned short* ip = idx + (size_t)row * MAXNZ;
    const float* nb = norm + (b << 12);
    for (int t = lane; t < c; t += 64) {
        unsigned short j = __builtin_nontemporal_load(ip + t);
        sj[wave][t] = j;
        sn[wave][t] = nb[j];
    }
    __syncthreads();

    const unsigned short* hp = h + ((size_t)(b << 12)) * DD + l32 * 8;
    float a0=0.f,a1=0.f,a2=0.f,a3=0.f,a4=0.f,a5=0.f,a6=0.f,a7=0.f;
    int t = half;
    for (; t + 6 < c; t += 8) {
        int j0 = sj[wave][t + 0]; float w0 = sn[wave][t + 0];
        int j1 = sj[wave][t + 2]; float w1 = sn[wave][t + 2];
        int j2 = sj[wave][t + 4]; float w2 = sn[wave][t + 4];
        int j3 = sj[wave][t + 6]; float w3 = sn[wave][t + 6];
        u16x8e v0 = *(const u16x8e*)(hp + (size_t)j0 * DD);
        u16x8e v1 = *(const u16x8e*)(hp + (size_t)j1 * DD);
        u16x8e v2 = *(const u16x8e*)(hp + (size_t)j2 * DD);
        u16x8e v3 = *(const u16x8e*)(hp + (size_t)j3 * DD);
        a0 += w0*bf2f(v0[0]) + w1*bf2f(v1[0]) + w2*bf2f(v2[0]) + w3*bf2f(v3[0]);
        a1 += w0*bf2f(v0[1]) + w1*bf2f(v1[1]) + w2*bf2f(v2[1]) + w3*bf2f(v3[1]);
        a2 += w0*bf2f(v0[2]) + w1*bf2f(v1[2]) + w2*bf2f(v2[2]) + w3*bf2f(v3[2]);
        a3 += w0*bf2f(v0[3]) + w1*bf2f(v1[3]) + w2*bf2f(v2[3]) + w3*bf2f(v3[3]);
        a4 += w0*bf2f(v0[4]) + w1*bf2f(v1[4]) + w2*bf2f(v2[4]) + w3*bf2f(v3[4]);
        a5 += w0*bf2f(v0[5]) + w1*bf2f(v1[5]) + w2*bf2f(v2[5]) + w3*bf2f(v3[5]);
        a6 += w0*bf2f(v0[6]) + w1*bf2f(v1[6]) + w2*bf2f(v2[6]) + w3*bf2f(v3[6]);
        a7 += w0*bf2f(v0[7]) + w1*bf2f(v1[7]) + w2*bf2f(v2[7]) + w3*bf2f(v3[7]);
    }
    for (; t < c; t += 2) {
        int j = sj[wave][t]; float wv = sn[wave][t];
        u16x8e v = *(const u16x8e*)(hp + (size_t)j * DD);
        a0 += wv*bf2f(v[0]); a1 += wv*bf2f(v[1]);
        a2 += wv*bf2f(v[2]); a3 += wv*bf2f(v[3]);
        a4 += wv*bf2f(v[4]); a5 += wv*bf2f(v[5]);
        a6 += wv*bf2f(v[6]); a7 += wv*bf2f(v[7]);
    }

    a0 += __shfl_xor(a0, 32); a1 += __shfl_xor(a1, 32);
    a2 += __shfl_xor(a2, 32); a3 += __shfl_xor(a3, 32);
    a4 += __shfl_xor(a4, 32); a5 += __shfl_xor(a5, 32);
    a6 += __shfl_xor(a6, 32); a7 += __shfl_xor(a7, 32);

    if (half == 0) {
        const float nrm = norm[row];
        const size_t off = (size_t)row * DD + l32 * 8;
        u16x8e hv = __builtin_nontemporal_load((const u16x8e*)(het + off));
        u16x8e gv = __builtin_nontemporal_load((const u16x8e*)(gate + off));
        float acc[8] = {a0,a1,a2,a3,a4,a5,a6,a7};
        f32x4e o0, o1;
#pragma unroll
        for (int e = 0; e < 8; ++e) {
            float fhom = acc[e] * nrm;
            float fh = bf2f(hv[e]);
            float g  = bf2f(gv[e]);
            float val = g * fhom + (1.f - g) * fh;
            float rr = (val > 0.f) ? val : (expf(val) - 1.f);
            if (e < 4) o0[e] = rr; else o1[e - 4] = rr;
        }
        __builtin_nontemporal_store(o0, (f32x4e*)(out + off));
        __builtin_nontemporal_store(o1, (f32x4e*)(out + off + 4));
    }
}

extern "C" void kernel_launch(void* const* d_in, const int* in_sizes, int n_in,
                              void* d_out, int out_size, void* d_ws, size_t ws_size,
                              hipStream_t stream) {
    const float* x     = (const float*)d_in[0];
    const float* adj   = (const float*)d_in[1];
    const float* theta = (const float*)d_in[2];
    const float* Wh    = (const float*)d_in[3];
    const float* Wt    = (const float*)d_in[4];
    const float* bt    = (const float*)d_in[5];
    float* out = (float*)d_out;

    char* w = (char*)d_ws;
    float* norm          = (float*)w;
    int*   cnt           = (int*)(w + (size_t)MM * 4);
    unsigned short* idx  = (unsigned short*)(w + (size_t)MM * 8);
    unsigned short* h    = (unsigned short*)(w + (size_t)MM * 8 + (size_t)MM * MAXNZ * 2);
    unsigned short* het  = h + (size_t)MM * DD;
    unsigned short* gate = het + (size_t)MM * DD;
    unsigned short* wb   = gate + (size_t)MM * DD;   // 384 KB (xb eliminated)

    k_cvt<<<dim3(192), dim3(256), 0, stream>>>(theta, Wh, Wt, wb);
    k_prep<<<dim3(TOTAL_BLKS), dim3(256), 0, stream>>>(x, wb, bt, adj,
                                                       norm, cnt, idx, h, het, gate);
    k_spmm<<<dim3(MM / 4), dim3(256), 0, stream>>>(h, het, gate, norm, cnt, idx, out);
}

// Round 18
// 90.188 us; speedup vs baseline: 1.0715x; 1.0715x over previous
//
#include <hip/hip_runtime.h>
#include <hip/hip_bf16.h>

#define BB 4
#define NN 4096
#define DD 256
#define MM (BB * NN)      // 16384 rows
#define MAXNZ 128
// grid: 1024 groups x 7 blocks = 3 GEMM + 4 deg (deg block = 4 waves = 4 rows)
#define GPER 7
#define TOTAL_BLKS (1024 * GPER)   // 7168

using bf16x8 = __attribute__((ext_vector_type(8))) __bf16;
using f32x4  = __attribute__((ext_vector_type(4))) float;
using f32x4e = __attribute__((ext_vector_type(4))) float;
using u16x8e = __attribute__((ext_vector_type(8))) unsigned short;

__device__ __forceinline__ unsigned short f2bf(float f) {
    union { float f; unsigned u; } x; x.f = f;
    unsigned r = x.u + 0x7fffu + ((x.u >> 16) & 1u);
    return (unsigned short)(r >> 16);
}
__device__ __forceinline__ float bf2f(unsigned short s) {
    union { unsigned u; float f; } x; x.u = ((unsigned)s) << 16;
    return x.f;
}

__device__ __forceinline__ void gload16(const void* g, void* l) {
    __builtin_amdgcn_global_load_lds(
        (const __attribute__((address_space(1))) unsigned int*)g,
        (__attribute__((address_space(3))) unsigned int*)l,
        16, 0, 0);
}

// ---------------- kernel 0: one-time bf16 conversion ----------------
__global__ __launch_bounds__(256) void k_cvt(const float* __restrict__ x,
                                             const float* __restrict__ theta,
                                             const float* __restrict__ Wh,
                                             const float* __restrict__ Wt,
                                             unsigned short* __restrict__ xb,
                                             unsigned short* __restrict__ wb) {
    const int bx = blockIdx.x;
    const int tid = threadIdx.x;
    if (bx < 4096) {
        size_t e4 = (size_t)bx * 256 + tid;
        f32x4e v = __builtin_nontemporal_load((const f32x4e*)x + e4);
        ushort4 o;
        o.x = f2bf(v[0]); o.y = f2bf(v[1]); o.z = f2bf(v[2]); o.w = f2bf(v[3]);
        *(ushort4*)(xb + e4 * 4) = o;
    } else {
        int wt = (bx - 4096) * 256 + tid;
        int s   = wt >> 14;
        int rem = wt & 16383;
        int k   = rem >> 6;
        int n4  = (rem & 63) << 2;
        const float* W = (s == 0) ? theta : ((s == 1) ? Wh : Wt);
        f32x4e v = __builtin_nontemporal_load((const f32x4e*)(W + k * DD + n4));
        unsigned short* dst = wb + ((size_t)s << 16);
        dst[(size_t)(n4 + 0) * DD + k] = f2bf(v[0]);
        dst[(size_t)(n4 + 1) * DD + k] = f2bf(v[1]);
        dst[(size_t)(n4 + 2) * DD + k] = f2bf(v[2]);
        dst[(size_t)(n4 + 3) * DD + k] = f2bf(v[3]);
    }
}

// ------------- fused kernel: deg scan + triple GEMM (R16 = best verified) -------------
__global__ __launch_bounds__(256) void k_prep(const unsigned short* __restrict__ xb,
                                              const unsigned short* __restrict__ wb,
                                              const float* __restrict__ bt,
                                              const float* __restrict__ adj,
                                              float* __restrict__ norm,
                                              int* __restrict__ cnt,
                                              unsigned short* __restrict__ idx,
                                              unsigned short* __restrict__ h,
                                              unsigned short* __restrict__ het,
                                              unsigned short* __restrict__ gate) {
    __shared__ __align__(16) unsigned short AB[8192];     // GEMM: A [0,4096), B [4096,8192)

    const int bx  = blockIdx.x;
    const int q   = bx / GPER;
    const int r   = bx % GPER;
    const int tid = threadIdx.x;
    const int wave = tid >> 6;
    const int lane = tid & 63;

    if (r < 3) {
        // ---------------- GEMM role ----------------
        const int g   = q * 3 + r;
        const int m0  = (g / 12) * 64;
        const int yb  = g % 12;
        const int seg = yb >> 2;
        const int n0  = (yb & 3) * 64;

        const int lm = lane & 15;
        const int kg = lane >> 4;
        const int wm = (wave >> 1) * 32;
        const int wn = (wave & 1) * 32;

        const int rsub = lane >> 3;
        const int ksw  = 8 * ((lane & 7) ^ rsub);

        const unsigned short* wseg = wb + ((size_t)seg << 16);

        f32x4 acc[2][2] = {};

        for (int kt = 0; kt < 4; ++kt) {
            const int k0 = kt * 64;
#pragma unroll
            for (int it = 0; it < 2; ++it) {
                int t = wave * 2 + it;
                const unsigned short* ga = xb + (size_t)(m0 + t * 8 + rsub) * DD + k0 + ksw;
                gload16(ga, &AB[t * 512]);
                const unsigned short* gb = wseg + (size_t)(n0 + t * 8 + rsub) * DD + k0 + ksw;
                gload16(gb, &AB[4096 + t * 512]);
            }
            __syncthreads();
#pragma unroll
            for (int ks = 0; ks < 2; ++ks) {
                const int cb = ks * 64 + kg * 16;
                bf16x8 a[2], b[2];
#pragma unroll
                for (int i = 0; i < 2; ++i) {
                    int rw = wm + i * 16 + lm;
                    a[i] = *(const bf16x8*)((const char*)AB + rw * 128 + (cb ^ ((rw & 7) << 4)));
                }
#pragma unroll
                for (int j = 0; j < 2; ++j) {
                    int rw = wn + j * 16 + lm;
                    b[j] = *(const bf16x8*)((const char*)AB + 8192 + rw * 128 + (cb ^ ((rw & 7) << 4)));
                }
#pragma unroll
                for (int i = 0; i < 2; ++i)
#pragma unroll
                    for (int j = 0; j < 2; ++j)
                        acc[i][j] = __builtin_amdgcn_mfma_f32_16x16x32_bf16(a[i], b[j], acc[i][j], 0, 0, 0);
            }
            __syncthreads();
        }

        const int rbase = (lane >> 4) * 4;
#pragma unroll
        for (int i = 0; i < 2; ++i) {
#pragma unroll
            for (int j = 0; j < 2; ++j) {
                int cseg = n0 + wn + j * 16 + lm;
#pragma unroll
                for (int rr = 0; rr < 4; ++rr) {
                    int grow = m0 + wm + i * 16 + rbase + rr;
                    float v = acc[i][j][rr];
                    size_t off = (size_t)grow * DD + cseg;
                    if (seg == 0) {
                        h[off] = f2bf(v);
                    } else if (seg == 1) {
                        het[off] = f2bf(v);
                    } else {
                        float gt = 1.f / (1.f + expf(-(v + bt[cseg])));
                        gate[off] = f2bf(gt);
                    }
                }
            }
        }
    } else {
        // -------- deg role: wave-per-row, 2x8-chunk register compaction --------
        const int drow = (q * 4 + (r - 3)) * 4 + wave;
        const float4* arow4 = (const float4*)(adj + (size_t)drow * NN);

        unsigned long long mask = 0ull;
#pragma unroll 1
        for (int hf = 0; hf < 2; ++hf) {
            float4 v[8];
#pragma unroll
            for (int s = 0; s < 8; ++s) v[s] = arow4[hf * 512 + s * 64 + lane];
#pragma unroll
            for (int s = 0; s < 8; ++s) {
                int base = 4 * (hf * 8 + s);
                if (v[s].x != 0.f) mask |= 1ull << (base + 0);
                if (v[s].y != 0.f) mask |= 1ull << (base + 1);
                if (v[s].z != 0.f) mask |= 1ull << (base + 2);
                if (v[s].w != 0.f) mask |= 1ull << (base + 3);
            }
        }

        const int cntl = __popcll(mask);
        int inc = cntl;
#pragma unroll
        for (int d = 1; d < 64; d <<= 1) {
            int t = __shfl_up(inc, d);
            if (lane >= d) inc += t;
        }
        const int excl  = inc - cntl;
        const int total = __shfl(inc, 63);

        unsigned long long m = mask;
        int slot = excl;
        while (m) {
            int bpos = __ffsll((unsigned long long)m) - 1;
            m &= m - 1;
            if (slot < MAXNZ) {
                int col = ((bpos >> 2) << 8) + (lane << 2) + (bpos & 3);
                idx[(size_t)drow * MAXNZ + slot] = (unsigned short)col;
            }
            ++slot;
        }
        if (lane == 0) {
            cnt[drow]  = total < MAXNZ ? total : MAXNZ;
            norm[drow] = rsqrtf((float)total + 1e-6f);
        }
    }
}

// ---------------- kernel 2: gather-SpMM + blend + ELU ----------------
__global__ __launch_bounds__(256) void k_spmm(const unsigned short* __restrict__ h,
                                              const unsigned short* __restrict__ het,
                                              const unsigned short* __restrict__ gate,
                                              const float* __restrict__ norm,
                                              const int* __restrict__ cnt,
                                              const unsigned short* __restrict__ idx,
                                              float* __restrict__ out) {
    __shared__ unsigned short sj[4][MAXNZ];
    __shared__ float sn[4][MAXNZ];
    const int wave = threadIdx.x >> 6;
    const int lane = threadIdx.x & 63;
    const int half = lane >> 5;
    const int l32  = lane & 31;
    const int row  = blockIdx.x * 4 + wave;
    const int b    = row >> 12;
    int c = cnt[row];
    if (c > MAXNZ) c = MAXNZ;
    const unsigned short* ip = idx + (size_t)row * MAXNZ;
    const float* nb = norm + (b << 12);
    for (int t = lane; t < c; t += 64) {
        unsigned short j = __builtin_nontemporal_load(ip + t);
        sj[wave][t] = j;
        sn[wave][t] = nb[j];
    }
    __syncthreads();

    const unsigned short* hp = h + ((size_t)(b << 12)) * DD + l32 * 8;
    float a0=0.f,a1=0.f,a2=0.f,a3=0.f,a4=0.f,a5=0.f,a6=0.f,a7=0.f;
    int t = half;
    for (; t + 6 < c; t += 8) {
        int j0 = sj[wave][t + 0]; float w0 = sn[wave][t + 0];
        int j1 = sj[wave][t + 2]; float w1 = sn[wave][t + 2];
        int j2 = sj[wave][t + 4]; float w2 = sn[wave][t + 4];
        int j3 = sj[wave][t + 6]; float w3 = sn[wave][t + 6];
        u16x8e v0 = *(const u16x8e*)(hp + (size_t)j0 * DD);
        u16x8e v1 = *(const u16x8e*)(hp + (size_t)j1 * DD);
        u16x8e v2 = *(const u16x8e*)(hp + (size_t)j2 * DD);
        u16x8e v3 = *(const u16x8e*)(hp + (size_t)j3 * DD);
        a0 += w0*bf2f(v0[0]) + w1*bf2f(v1[0]) + w2*bf2f(v2[0]) + w3*bf2f(v3[0]);
        a1 += w0*bf2f(v0[1]) + w1*bf2f(v1[1]) + w2*bf2f(v2[1]) + w3*bf2f(v3[1]);
        a2 += w0*bf2f(v0[2]) + w1*bf2f(v1[2]) + w2*bf2f(v2[2]) + w3*bf2f(v3[2]);
        a3 += w0*bf2f(v0[3]) + w1*bf2f(v1[3]) + w2*bf2f(v2[3]) + w3*bf2f(v3[3]);
        a4 += w0*bf2f(v0[4]) + w1*bf2f(v1[4]) + w2*bf2f(v2[4]) + w3*bf2f(v3[4]);
        a5 += w0*bf2f(v0[5]) + w1*bf2f(v1[5]) + w2*bf2f(v2[5]) + w3*bf2f(v3[5]);
        a6 += w0*bf2f(v0[6]) + w1*bf2f(v1[6]) + w2*bf2f(v2[6]) + w3*bf2f(v3[6]);
        a7 += w0*bf2f(v0[7]) + w1*bf2f(v1[7]) + w2*bf2f(v2[7]) + w3*bf2f(v3[7]);
    }
    for (; t < c; t += 2) {
        int j = sj[wave][t]; float wv = sn[wave][t];
        u16x8e v = *(const u16x8e*)(hp + (size_t)j * DD);
        a0 += wv*bf2f(v[0]); a1 += wv*bf2f(v[1]);
        a2 += wv*bf2f(v[2]); a3 += wv*bf2f(v[3]);
        a4 += wv*bf2f(v[4]); a5 += wv*bf2f(v[5]);
        a6 += wv*bf2f(v[6]); a7 += wv*bf2f(v[7]);
    }

    a0 += __shfl_xor(a0, 32); a1 += __shfl_xor(a1, 32);
    a2 += __shfl_xor(a2, 32); a3 += __shfl_xor(a3, 32);
    a4 += __shfl_xor(a4, 32); a5 += __shfl_xor(a5, 32);
    a6 += __shfl_xor(a6, 32); a7 += __shfl_xor(a7, 32);

    if (half == 0) {
        const float nrm = norm[row];
        const size_t off = (size_t)row * DD + l32 * 8;
        u16x8e hv = __builtin_nontemporal_load((const u16x8e*)(het + off));
        u16x8e gv = __builtin_nontemporal_load((const u16x8e*)(gate + off));
        float acc[8] = {a0,a1,a2,a3,a4,a5,a6,a7};
        f32x4e o0, o1;
#pragma unroll
        for (int e = 0; e < 8; ++e) {
            float fhom = acc[e] * nrm;
            float fh = bf2f(hv[e]);
            float g  = bf2f(gv[e]);
            float val = g * fhom + (1.f - g) * fh;
            float rr = (val > 0.f) ? val : (expf(val) - 1.f);
            if (e < 4) o0[e] = rr; else o1[e - 4] = rr;
        }
        __builtin_nontemporal_store(o0, (f32x4e*)(out + off));
        __builtin_nontemporal_store(o1, (f32x4e*)(out + off + 4));
    }
}

extern "C" void kernel_launch(void* const* d_in, const int* in_sizes, int n_in,
                              void* d_out, int out_size, void* d_ws, size_t ws_size,
                              hipStream_t stream) {
    const float* x     = (const float*)d_in[0];
    const float* adj   = (const float*)d_in[1];
    const float* theta = (const float*)d_in[2];
    const float* Wh    = (const float*)d_in[3];
    const float* Wt    = (const float*)d_in[4];
    const float* bt    = (const float*)d_in[5];
    float* out = (float*)d_out;

    char* w = (char*)d_ws;
    float* norm          = (float*)w;
    int*   cnt           = (int*)(w + (size_t)MM * 4);
    unsigned short* idx  = (unsigned short*)(w + (size_t)MM * 8);
    unsigned short* h    = (unsigned short*)(w + (size_t)MM * 8 + (size_t)MM * MAXNZ * 2);
    unsigned short* het  = h + (size_t)MM * DD;
    unsigned short* gate = het + (size_t)MM * DD;
    unsigned short* xb   = gate + (size_t)MM * DD;
    unsigned short* wb   = xb + (size_t)MM * DD;

    k_cvt<<<dim3(4288), dim3(256), 0, stream>>>(x, theta, Wh, Wt, xb, wb);
    k_prep<<<dim3(TOTAL_BLKS), dim3(256), 0, stream>>>(xb, wb, bt, adj,
                                                       norm, cnt, idx, h, het, gate);
    k_spmm<<<dim3(MM / 4), dim3(256), 0, stream>>>(h, het, gate, norm, cnt, idx, out);
}